// Round 5
// baseline (19936.723 us; speedup 1.0000x reference)
//
#include <hip/hip_runtime.h>
#include <stdint.h>

#define HDIM 96
#define G3   288
#define TLEN 239
#define BB   16
#define NBLK 256    // 4096 / 16
#define NTHR 768    // 12 waves: 6 gh + 6 gi
#define TSLAB (4096 * 96)   // elems per t-slab in t-major layout

// h ring: 32 slots, flattened. Row stride 104 f16 (208 B, 8B-aligned rows),
// slot stride 16*104+4 = 1668 f16 = 834 dw; gcd(834,32)=2 -> 2-way on the
// 32-lane t-axis flush reads (free, m136). Total 32*1668*2 = 106,752 B.
#define HSLOT 1668
#define HROW  104

typedef _Float16 f16;
typedef f16  f16x8 __attribute__((ext_vector_type(8)));
typedef f16  f16x4 __attribute__((ext_vector_type(4)));
typedef float f32x4 __attribute__((ext_vector_type(4)));

__device__ __forceinline__ float sigm(float x)  { return 1.f / (1.f + __expf(-x)); }
__device__ __forceinline__ float tanh_(float x) { return 1.f - 2.f / (1.f + __expf(2.f * x)); }

// ============================================================================
// Fast path: t-major f16 activations.
//   xin : f16 [T][4096][96] (ignored for layer 0 — GRU input is zeros)
//   outp: !FINAL_OUT -> f16 [T][4096][96];  FINAL_OUT -> float [4096][96][239]
// ============================================================================
template<bool HAS_X, bool FINAL_OUT>
__global__ __launch_bounds__(NTHR, 3)
void gru_layer_tm(const f16* __restrict__ xin, void* __restrict__ outp,
                  const float* __restrict__ zin, const float* __restrict__ cin,
                  const float* __restrict__ fc1w, const float* __restrict__ fc1b,
                  const float* __restrict__ wih, const float* __restrict__ whh,
                  const float* __restrict__ bih, const float* __restrict__ bhh,
                  int layer)
{
  __shared__ f16   hbuf[32][HSLOT];     // 32-step h ring / FINAL staging
  __shared__ float gi_buf[16][300];
  __shared__ float xcat[4][512];
  __shared__ float fc1o[4][384];

  const int tid = threadIdx.x;
  const int wv  = tid >> 6;
  const int ln  = tid & 63;
  const int r0  = blockIdx.x * BB;
  const int g   = ln >> 4;
  const int lm  = ln & 15;

  // ---- fc1 -> h0 (reshape semantics: h0[l][b][h] = fc1o[l*1024+b/4][(b%4)*96+h])
  const int base_in = layer * 1024 + (r0 >> 2);
  for (int i = tid; i < 4 * 512; i += NTHR) {
    int q = i >> 9, k = i & 511;
    xcat[q][k] = (k < 256) ? zin[(base_in + q) * 256 + k]
                           : cin[(base_in + q) * 256 + (k - 256)];
  }
  __syncthreads();
  for (int of = wv * 32; of < wv * 32 + 32; ++of) {
    float wreg[8];
    #pragma unroll
    for (int i = 0; i < 8; ++i) wreg[i] = fc1w[of * 512 + ln + 64 * i];
    float s[4];
    #pragma unroll
    for (int q = 0; q < 4; ++q) {
      float a = 0.f;
      #pragma unroll
      for (int i = 0; i < 8; ++i) a += wreg[i] * xcat[q][ln + 64 * i];
      s[q] = a;
    }
    #pragma unroll
    for (int off = 32; off; off >>= 1)
      #pragma unroll
      for (int q = 0; q < 4; ++q) s[q] += __shfl_down(s[q], off);
    if (ln == 0) {
      float b = fc1b[of];
      #pragma unroll
      for (int q = 0; q < 4; ++q) {
        float v = s[q] + b;
        fc1o[q][of] = (v >= 0.f) ? v : 0.2f * v;
      }
    }
  }
  __syncthreads();

  const bool is_gh = (wv < 6);
  const int  wg    = is_gh ? wv : wv - 6;
  const int  col   = wg * 16 + lm;

  // weight B-fragments: B[k][n]=w[nt*96+col][k]; shorts 0-3: k=kt*32+4g+j, 4-7: +16
  f16x8 wf[3][3];
  if (is_gh || HAS_X) {
    const float* wmat = is_gh ? whh : wih;
    #pragma unroll
    for (int nt = 0; nt < 3; ++nt)
      #pragma unroll
      for (int kt = 0; kt < 3; ++kt) {
        const float* src = wmat + (nt * 96 + col) * 96 + kt * 32 + 4 * g;
        f16x8 f;
        #pragma unroll
        for (int j = 0; j < 4; ++j) { f[j] = (f16)src[j]; f[4 + j] = (f16)src[16 + j]; }
        wf[nt][kt] = f;
      }
  }

  float bir = 0, biz = 0, bin_ = 0, bhr = 0, bhz = 0, bhn = 0;
  float hprev[4] = {0, 0, 0, 0};
  if (is_gh) {
    bir = bih[col]; biz = bih[96 + col]; bin_ = bih[192 + col];
    bhr = bhh[col]; bhz = bhh[96 + col]; bhn = bhh[192 + col];
    #pragma unroll
    for (int j = 0; j < 4; ++j) {
      float h0v = fc1o[g][j * 96 + col];        // local row 4g+j
      hprev[j] = h0v;
      hbuf[31][(4 * g + j) * HROW + col] = (f16)h0v;   // slot for t-1 of t=0
    }
  }

  // gi waves: 2-deep x prefetch (t-major: 3 KB contiguous per block per step)
  f16x4 xa[2][6];
  size_t xoff = (size_t)(r0 + lm) * 96;
  if (!is_gh && HAS_X) {
    #pragma unroll
    for (int pb = 0; pb < 2; ++pb) {
      const f16* p = xin + (size_t)pb * TSLAB + xoff;
      #pragma unroll
      for (int kt = 0; kt < 3; ++kt) {
        xa[pb][kt * 2]     = *(const f16x4*)(p + kt * 32 + 4 * g);
        xa[pb][kt * 2 + 1] = *(const f16x4*)(p + kt * 32 + 16 + 4 * g);
      }
    }
  }
  __syncthreads();

  f16*   out16 = (f16*)outp;
  float* outf  = (float*)outp;

  for (int t = 0; t < TLEN; ++t) {
    const int slot_r = (t + 31) & 31;
    const int slot_w = t & 31;
    const f32x4 z4 = {0.f, 0.f, 0.f, 0.f};
    f32x4 acc[3] = {z4, z4, z4};

    // ---- phase A ----
    if (is_gh) {
      #pragma unroll
      for (int kt = 0; kt < 3; ++kt) {
        f16x4 lo = *(const f16x4*)&hbuf[slot_r][lm * HROW + kt * 32 + 4 * g];
        f16x4 hi = *(const f16x4*)&hbuf[slot_r][lm * HROW + kt * 32 + 16 + 4 * g];
        f16x8 a;
        #pragma unroll
        for (int j = 0; j < 4; ++j) { a[j] = lo[j]; a[4 + j] = hi[j]; }
        #pragma unroll
        for (int nt = 0; nt < 3; ++nt)
          acc[nt] = __builtin_amdgcn_mfma_f32_16x16x32_f16(a, wf[nt][kt], acc[nt], 0, 0, 0);
      }
    } else if (HAS_X) {
      const int cur = t & 1;
      #pragma unroll
      for (int kt = 0; kt < 3; ++kt) {
        f16x4 lo = xa[cur][kt * 2], hi = xa[cur][kt * 2 + 1];
        f16x8 a;
        #pragma unroll
        for (int j = 0; j < 4; ++j) { a[j] = lo[j]; a[4 + j] = hi[j]; }
        #pragma unroll
        for (int nt = 0; nt < 3; ++nt)
          acc[nt] = __builtin_amdgcn_mfma_f32_16x16x32_f16(a, wf[nt][kt], acc[nt], 0, 0, 0);
      }
      #pragma unroll
      for (int nt = 0; nt < 3; ++nt)
        #pragma unroll
        for (int reg = 0; reg < 4; ++reg)
          gi_buf[4 * g + reg][nt * 96 + col] = acc[nt][reg];
      if (t + 2 < TLEN) {   // refill buffer just consumed
        const f16* p = xin + (size_t)(t + 2) * TSLAB + xoff;
        #pragma unroll
        for (int kt = 0; kt < 3; ++kt) {
          xa[cur][kt * 2]     = *(const f16x4*)(p + kt * 32 + 4 * g);
          xa[cur][kt * 2 + 1] = *(const f16x4*)(p + kt * 32 + 16 + 4 * g);
        }
      }
    }
    __syncthreads();

    // ---- phase B: gates (gh waves) ----
    if (is_gh) {
      #pragma unroll
      for (int reg = 0; reg < 4; ++reg) {
        float gr = acc[0][reg] + bhr;
        float gz = acc[1][reg] + bhz;
        float gn = acc[2][reg] + bhn;
        float ir = bir, iz = biz, in_ = bin_;
        if (HAS_X) {
          ir  += gi_buf[4 * g + reg][col];
          iz  += gi_buf[4 * g + reg][96 + col];
          in_ += gi_buf[4 * g + reg][192 + col];
        }
        float r  = sigm(ir + gr);
        float zg = sigm(iz + gz);
        float n  = tanh_(in_ + r * gn);
        float hn = (1.f - zg) * n + zg * hprev[reg];
        hprev[reg] = hn;
        f16 h16 = (f16)hn;
        hbuf[slot_w][(4 * g + reg) * HROW + col] = h16;
        if (!FINAL_OUT)
          __builtin_nontemporal_store(
              h16, &out16[(size_t)t * TSLAB + (r0 + 4 * g + reg) * 96 + col]);
      }
    }
    __syncthreads();

    // ---- FINAL: flush 32-step LDS ring to fp32 [B][H][T] ----
    // Half-wave = 32 lanes = 32 consecutive t's of one (row,col): 128 B runs.
    if (FINAL_OUT && (((t & 31) == 31) || (t == TLEN - 1))) {
      const int t0 = t & ~31;
      const int ns = t - t0 + 1;
      const int tl = ln & 31;
      const int hw = ln >> 5;            // half-wave: which rc of the pair
      if (tl < ns) {
        #pragma unroll 4
        for (int i = 0; i < 64; ++i) {
          int rc   = wv * 128 + i * 2 + hw;          // [0,1536)
          int brow = (rc * 683) >> 16;               // /96
          int c    = rc - brow * 96;
          float v  = (float)hbuf[tl][brow * HROW + c];
          __builtin_nontemporal_store(
              v, &outf[((uint32_t)(r0 + brow) * 96 + c) * 239 + t0 + tl]);
        }
      }
      // next hbuf write (slot 0 of next window) is after the next phase-A barrier ✔
    }
  }
}

// ============================================================================
// Fallback (ws too small): in-place fp32 [B][H][T] path — slow, correct.
// ============================================================================
template<bool HAS_X>
__global__ __launch_bounds__(NTHR, 3)
void gru_layer_ip(float* seq,
                  const float* __restrict__ zin, const float* __restrict__ cin,
                  const float* __restrict__ fc1w, const float* __restrict__ fc1b,
                  const float* __restrict__ wih, const float* __restrict__ whh,
                  const float* __restrict__ bih, const float* __restrict__ bhh,
                  int layer)
{
  __shared__ f16   h_plane[2][16][104];
  __shared__ float gi_buf[16][300];
  __shared__ float xcat[4][512];
  __shared__ float fc1o[4][384];

  const int tid = threadIdx.x;
  const int wv  = tid >> 6;
  const int ln  = tid & 63;
  const int r0  = blockIdx.x * BB;
  const int g   = ln >> 4;
  const int lm  = ln & 15;

  const int base_in = layer * 1024 + (r0 >> 2);
  for (int i = tid; i < 4 * 512; i += NTHR) {
    int q = i >> 9, k = i & 511;
    xcat[q][k] = (k < 256) ? zin[(base_in + q) * 256 + k]
                           : cin[(base_in + q) * 256 + (k - 256)];
  }
  __syncthreads();
  for (int of = wv * 32; of < wv * 32 + 32; ++of) {
    float wreg[8];
    #pragma unroll
    for (int i = 0; i < 8; ++i) wreg[i] = fc1w[of * 512 + ln + 64 * i];
    float s[4];
    #pragma unroll
    for (int q = 0; q < 4; ++q) {
      float a = 0.f;
      #pragma unroll
      for (int i = 0; i < 8; ++i) a += wreg[i] * xcat[q][ln + 64 * i];
      s[q] = a;
    }
    #pragma unroll
    for (int off = 32; off; off >>= 1)
      #pragma unroll
      for (int q = 0; q < 4; ++q) s[q] += __shfl_down(s[q], off);
    if (ln == 0) {
      float b = fc1b[of];
      #pragma unroll
      for (int q = 0; q < 4; ++q) {
        float v = s[q] + b;
        fc1o[q][of] = (v >= 0.f) ? v : 0.2f * v;
      }
    }
  }
  __syncthreads();

  const bool is_gh = (wv < 6);
  const int  wg    = is_gh ? wv : wv - 6;
  const int  col   = wg * 16 + lm;

  f16x8 wf[3][3];
  if (is_gh || HAS_X) {
    const float* wmat = is_gh ? whh : wih;
    #pragma unroll
    for (int nt = 0; nt < 3; ++nt)
      #pragma unroll
      for (int kt = 0; kt < 3; ++kt) {
        const float* src = wmat + (nt * 96 + col) * 96 + kt * 32 + 4 * g;
        f16x8 f;
        #pragma unroll
        for (int j = 0; j < 4; ++j) { f[j] = (f16)src[j]; f[4 + j] = (f16)src[16 + j]; }
        wf[nt][kt] = f;
      }
  }

  float bir = 0, biz = 0, bin_ = 0, bhr = 0, bhz = 0, bhn = 0;
  float hprev[4] = {0, 0, 0, 0};
  uint32_t obase[4] = {0, 0, 0, 0};
  if (is_gh) {
    bir = bih[col]; biz = bih[96 + col]; bin_ = bih[192 + col];
    bhr = bhh[col]; bhz = bhh[96 + col]; bhn = bhh[192 + col];
    #pragma unroll
    for (int j = 0; j < 4; ++j) {
      float h0v = fc1o[g][j * 96 + col];
      hprev[j] = h0v;
      h_plane[0][4 * g + j][col] = (f16)h0v;
      obase[j] = ((uint32_t)(r0 + 4 * g + j) * 96 + col) * 239;
    }
  }

  const float* xptr[6];
  float xc[6][4];
  if (!is_gh && HAS_X) {
    #pragma unroll
    for (int kt = 0; kt < 3; ++kt)
      #pragma unroll
      for (int hh = 0; hh < 2; ++hh)
        xptr[kt * 2 + hh] = seq + ((size_t)(r0 + lm) * 96 + kt * 32 + 16 * hh + 4 * g) * 239;
    #pragma unroll
    for (int f = 0; f < 6; ++f)
      #pragma unroll
      for (int j = 0; j < 4; ++j) xc[f][j] = xptr[f][j * 239];
  }
  __syncthreads();

  float hist[4][8];
  for (int t0 = 0; t0 < TLEN; t0 += 8) {
    const int nsteps = (TLEN - t0 < 8) ? (TLEN - t0) : 8;
    #pragma unroll
    for (int s = 0; s < 8; ++s) {
      if (s < nsteps) {
        const int t = t0 + s;
        const int buf = t & 1;
        const f32x4 z4 = {0.f, 0.f, 0.f, 0.f};
        f32x4 acc[3] = {z4, z4, z4};
        if (is_gh) {
          #pragma unroll
          for (int kt = 0; kt < 3; ++kt) {
            f16x4 lo = *(const f16x4*)&h_plane[buf][lm][kt * 32 + 4 * g];
            f16x4 hi = *(const f16x4*)&h_plane[buf][lm][kt * 32 + 16 + 4 * g];
            f16x8 a;
            #pragma unroll
            for (int j = 0; j < 4; ++j) { a[j] = lo[j]; a[4 + j] = hi[j]; }
            #pragma unroll
            for (int nt = 0; nt < 3; ++nt)
              acc[nt] = __builtin_amdgcn_mfma_f32_16x16x32_f16(a, wf[nt][kt], acc[nt], 0, 0, 0);
          }
        } else if (HAS_X) {
          #pragma unroll
          for (int kt = 0; kt < 3; ++kt) {
            f16x8 a;
            #pragma unroll
            for (int j = 0; j < 4; ++j) { a[j] = (f16)xc[2 * kt][j]; a[4 + j] = (f16)xc[2 * kt + 1][j]; }
            #pragma unroll
            for (int nt = 0; nt < 3; ++nt)
              acc[nt] = __builtin_amdgcn_mfma_f32_16x16x32_f16(a, wf[nt][kt], acc[nt], 0, 0, 0);
          }
          #pragma unroll
          for (int nt = 0; nt < 3; ++nt)
            #pragma unroll
            for (int reg = 0; reg < 4; ++reg)
              gi_buf[4 * g + reg][nt * 96 + col] = acc[nt][reg];
          if (t + 1 < TLEN) {
            #pragma unroll
            for (int f = 0; f < 6; ++f)
              #pragma unroll
              for (int j = 0; j < 4; ++j) xc[f][j] = xptr[f][(t + 1) + j * 239];
          }
        }
        __syncthreads();
        if (is_gh) {
          #pragma unroll
          for (int reg = 0; reg < 4; ++reg) {
            float gr = acc[0][reg] + bhr;
            float gz = acc[1][reg] + bhz;
            float gn = acc[2][reg] + bhn;
            float ir = bir, iz = biz, in_ = bin_;
            if (HAS_X) {
              ir  += gi_buf[4 * g + reg][col];
              iz  += gi_buf[4 * g + reg][96 + col];
              in_ += gi_buf[4 * g + reg][192 + col];
            }
            float r  = sigm(ir + gr);
            float zg = sigm(iz + gz);
            float n  = tanh_(in_ + r * gn);
            float hn = (1.f - zg) * n + zg * hprev[reg];
            hprev[reg] = hn;
            hist[reg][s] = hn;
            h_plane[buf ^ 1][4 * g + reg][col] = (f16)hn;
          }
        }
        __syncthreads();
      }
    }
    if (is_gh) {
      #pragma unroll
      for (int reg = 0; reg < 4; ++reg)
        #pragma unroll
        for (int q = 0; q < 8; ++q)
          if (q < nsteps) seq[obase[reg] + (uint32_t)(t0 + q)] = hist[reg][q];
    }
  }
}

extern "C" void kernel_launch(void* const* d_in, const int* in_sizes, int n_in,
                              void* d_out, int out_size, void* d_ws, size_t ws_size,
                              hipStream_t stream) {
  const float* zin  = (const float*)d_in[0];
  const float* cin  = (const float*)d_in[1];
  const float* fc1w = (const float*)d_in[2];
  const float* fc1b = (const float*)d_in[3];
  const float* wih  = (const float*)d_in[4];
  const float* whh  = (const float*)d_in[5];
  const float* bih  = (const float*)d_in[6];
  const float* bhh  = (const float*)d_in[7];
  (void)in_sizes; (void)n_in; (void)out_size;

  const size_t need = (size_t)TLEN * TSLAB * sizeof(f16);   // 187,957,248 B
  dim3 grid(NBLK), blk(NTHR);

  if (ws_size >= need) {
    f16* bufA = (f16*)d_ws;                                   // 188 MB scratch
    f16* bufB = (f16*)((char*)d_out + need);                  // upper half of d_out
    // L0: zeros -> A
    gru_layer_tm<false, false><<<grid, blk, 0, stream>>>(
        nullptr, bufA, zin, cin, fc1w, fc1b, wih, whh, bih, bhh, 0);
    // L1: A -> B
    gru_layer_tm<true, false><<<grid, blk, 0, stream>>>(
        bufA, bufB, zin, cin, fc1w, fc1b,
        wih + 1 * G3 * HDIM, whh + 1 * G3 * HDIM, bih + 1 * G3, bhh + 1 * G3, 1);
    // L2: B -> A
    gru_layer_tm<true, false><<<grid, blk, 0, stream>>>(
        bufB, bufA, zin, cin, fc1w, fc1b,
        wih + 2 * G3 * HDIM, whh + 2 * G3 * HDIM, bih + 2 * G3, bhh + 2 * G3, 2);
    // L3: A -> fp32 [B][H][T] (overwrites bufB region; bufB already consumed)
    gru_layer_tm<true, true><<<grid, blk, 0, stream>>>(
        bufA, d_out, zin, cin, fc1w, fc1b,
        wih + 3 * G3 * HDIM, whh + 3 * G3 * HDIM, bih + 3 * G3, bhh + 3 * G3, 3);
  } else {
    float* seq = (float*)d_out;
    gru_layer_ip<false><<<grid, blk, 0, stream>>>(seq, zin, cin, fc1w, fc1b,
                                                  wih, whh, bih, bhh, 0);
    for (int l = 1; l < 4; ++l)
      gru_layer_ip<true><<<grid, blk, 0, stream>>>(seq, zin, cin, fc1w, fc1b,
                                                   wih + l * G3 * HDIM, whh + l * G3 * HDIM,
                                                   bih + l * G3, bhh + l * G3, l);
  }
}